// Round 16
// baseline (46.686 us; speedup 1.0000x reference)
//
#include <hip/hip_runtime.h>

// PairwiseRankLoss: U=262144 users x G=64 items, K=2, MARGIN=0.3
// 4 users/wave group of 16 lanes, 4 items/lane. R16 = R15 with the pin
// fixed: "+v" on float4 was rejected ("tied indirect register inputs");
// pin the 12 scalar components individually instead.
//  Rotating 1-chunk register prefetch pinned by a keep-alive asm placed
//  AFTER process(): loads' first use is the bottom of the body, so the
//  scheduler issues them at the top and the vmcnt wait lands after ~900
//  cycles of compute. Compiler-tracked waitcnt, no manual hazards.
// Compute: GF(2)^3-remapped all-DPP signed-space bitonic, split vs ror8,
// a31 = max(lower32); index-embedded selection keys; LDS uniform gather.
// Deterministic two-stage reduction via d_ws.

static constexpr int kUsers = 262144;
static constexpr int kBlock = 256;                  // 4 waves / block
static constexpr int kGrid  = 2048;
static constexpr int kWavesPerBlock = kBlock / 64;
static constexpr int kTotalWaves = kGrid * kWavesPerBlock;   // 8192
static constexpr int kUsersPerWave = kUsers / kTotalWaves;   // 32
static constexpr int kIters = kUsersPerWave / 4;             // 8
static constexpr float kMargin = 0.3f;

template<int CTRL>
static __device__ __forceinline__ float movdppf(float x) {
    return __uint_as_float((unsigned)__builtin_amdgcn_mov_dpp(
        (int)__float_as_uint(x), CTRL, 0xF, 0xF, false));
}
template<int CTRL>
static __device__ __forceinline__ unsigned movdppu(unsigned x) {
    return (unsigned)__builtin_amdgcn_mov_dpp((int)x, CTRL, 0xF, 0xF, false);
}
static __device__ __forceinline__ float xorf(float x, unsigned m) {
    return __uint_as_float(__float_as_uint(x) ^ m);
}
static __device__ __forceinline__ float cnd(float mx, float mn,
                                            unsigned long long keep) {
    float d;
    asm("v_cndmask_b32 %0, %1, %2, %3" : "=v"(d) : "v"(mx), "v"(mn), "s"(keep));
    return d;
}
template<int CTRL>
static __device__ __forceinline__ float cexd(float w, unsigned long long keep) {
    const float p = movdppf<CTRL>(w);
    return cnd(fmaxf(w, p), fminf(w, p), keep);
}
static __device__ __forceinline__ unsigned umax_(unsigned a, unsigned b){ return a>b?a:b; }
static __device__ __forceinline__ unsigned umin_(unsigned a, unsigned b){ return a<b?a:b; }

#define CE2A(a, b) { float mn_=fminf(a,b), mx_=fmaxf(a,b); (a)=mn_; (b)=mx_; }
#define CE2D(a, b) { float mn_=fminf(a,b), mx_=fmaxf(a,b); (a)=mx_; (b)=mn_; }
#define FLIP4(m)   { w0=xorf(w0,m); w1=xorf(w1,m); w2=xorf(w2,m); w3=xorf(w3,m); }
#define CEX4(CTRL, keep) { w0=cexd<CTRL>(w0,keep); w1=cexd<CTRL>(w1,keep); \
                           w2=cexd<CTRL>(w2,keep); w3=cexd<CTRL>(w3,keep); }
#define FOLD2(m1, m2, CTRL) { \
    unsigned q1_ = movdppu<CTRL>(m1), q2_ = movdppu<CTRL>(m2); \
    unsigned lo_ = umin_(m1, q1_); \
    m1 = umax_(m1, q1_); \
    m2 = umax_(lo_, umax_(m2, q2_)); }

__global__ __launch_bounds__(kBlock, 8)
void prl_user_kernel(const float* __restrict__ y_hat,
                     const float* __restrict__ y_true,
                     const float* __restrict__ rnd,
                     float* __restrict__ partials)
{
    const int lane = threadIdx.x & 63;
    const int wv   = threadIdx.x >> 6;
    const int wid  = (blockIdx.x * kBlock + threadIdx.x) >> 6;
    const int t    = lane & 15;          // lane within user group
    const int g    = lane >> 4;          // user group (0..3) within wave

    // logical coords: tt = M^-1(physical t) for map {1,2,4}->{1,2,7}
    const int p2   = (t >> 2) & 1;
    const int tt0  = (t & 1) ^ p2;
    const int tt1  = ((t >> 1) & 1) ^ p2;
    const int tt2  = p2;
    const int half = (t >> 3) & 1;

    const unsigned SGN = 0x80000000u;
    const unsigned flipA = tt0 ? SGN : 0u;
    const unsigned flipB = (tt0 ^ tt1) ? SGN : 0u;
    const unsigned flipC = (tt1 ^ tt2) ? SGN : 0u;
    const unsigned flipD = (tt2 ^ half) ? SGN : 0u;   // + B-half descending
    const unsigned sgnB  = half ? SGN : 0u;
    const unsigned long long keep1 = __ballot(tt0 == 0);
    const unsigned long long keep2 = __ballot(tt1 == 0);
    const unsigned long long keep4 = __ballot(tt2 == 0);

    const unsigned cb = 63u - ((unsigned)t << 2);   // 63 - item_idx base

    // y_hat gather table: [wave][group][64] = 4 KB/block
    __shared__ __align__(16) float yh_tab[kWavesPerBlock][4][64];
    __shared__ float wsum[kWavesPerBlock];
    float* tab = &yh_tab[wv][g][0];

    auto process = [&](float4 vh, float4 vt, float4 vr) -> float {
        *reinterpret_cast<float4*>(tab + (t << 2)) = vh;

        // ---- signed-space bitonic, remapped lanes; halves A asc / B desc --
        float w0 = vt.x, w1 = vt.y, w2 = vt.z, w3 = vt.w;
        CE2A(w0, w1); CE2D(w2, w3);                    // k=2 (true space)
        FLIP4(flipA);
        CE2A(w0, w2); CE2A(w1, w3);                    // k=4 j=2
        CE2A(w0, w1); CE2A(w2, w3);                    //     j=1
        FLIP4(flipB);
        CEX4(0xB1, keep1);                             // k=8 j=4 (phys xor1)
        CE2A(w0, w2); CE2A(w1, w3);
        CE2A(w0, w1); CE2A(w2, w3);
        FLIP4(flipC);
        CEX4(0x4E, keep2);                             // k=16 j=8 (xor2)
        CEX4(0xB1, keep1);                             //      j=4
        CE2A(w0, w2); CE2A(w1, w3);
        CE2A(w0, w1); CE2A(w2, w3);
        FLIP4(flipD);
        CEX4(0x141, keep4);                            // k=32 j=16 (xor7)
        CEX4(0x4E, keep2);                             //      j=8
        CEX4(0xB1, keep1);                             //      j=4
        CE2A(w0, w2); CE2A(w1, w3);
        CE2A(w0, w1); CE2A(w2, w3);

        // unflip B half; split = min with ror8 partner
        w0 = xorf(w0, sgnB); w1 = xorf(w1, sgnB);
        w2 = xorf(w2, sgnB); w3 = xorf(w3, sgnB);
        const float l0 = fminf(w0, movdppf<0x128>(w0));
        const float l1 = fminf(w1, movdppf<0x128>(w1));
        const float l2 = fminf(w2, movdppf<0x128>(w2));
        const float l3 = fminf(w3, movdppf<0x128>(w3));

        // a31 = max of lower-32 (period-8 data; 3 fold steps)
        float m = fmaxf(fmaxf(l0, l1), fmaxf(l2, l3));
        m = fmaxf(m, movdppf<0x124>(m));
        m = fmaxf(m, movdppf<0x122>(m));
        m = fmaxf(m, movdppf<0x121>(m));
        const float a31 = m;                           // group-uniform

        // ---- selection keys: (r & ~63) | (63 - item_idx) ----
        const bool p0m = vt.x > a31, p1m = vt.y > a31,
                   p2m = vt.z > a31, p3m = vt.w > a31;
        const unsigned kk0 = (__float_as_uint(vr.x) & ~63u) | cb;
        const unsigned kk1 = (__float_as_uint(vr.y) & ~63u) | (cb - 1u);
        const unsigned kk2 = (__float_as_uint(vr.z) & ~63u) | (cb - 2u);
        const unsigned kk3 = (__float_as_uint(vr.w) & ~63u) | (cb - 3u);

        auto top2 = [&](unsigned k0, unsigned k1, unsigned k2, unsigned k3,
                        unsigned& m1, unsigned& m2) {
            const unsigned x1 = umax_(k0,k1), x2 = umin_(k0,k1);
            const unsigned y1 = umax_(k2,k3), y2 = umin_(k2,k3);
            m1 = umax_(x1,y1);
            m2 = umax_(umin_(x1,y1), umax_(x2,y2));
            FOLD2(m1, m2, 0x128);
            FOLD2(m1, m2, 0x124);
            FOLD2(m1, m2, 0x122);
            FOLD2(m1, m2, 0x121);
        };
        unsigned pm1, pm2, nm1, nm2;
        top2(p0m ? kk0 : 0u, p1m ? kk1 : 0u, p2m ? kk2 : 0u, p3m ? kk3 : 0u,
             pm1, pm2);
        top2(p0m ? 0u : kk0, p1m ? 0u : kk1, p2m ? 0u : kk2, p3m ? 0u : kk3,
             nm1, nm2);

        const float P0 = tab[(pm1 & 63u) ^ 63u];
        const float P1 = tab[(pm2 & 63u) ^ 63u];
        const float N0 = tab[(nm1 & 63u) ^ 63u];
        const float N1 = tab[(nm2 & 63u) ^ 63u];

        float s = 0.0f;
        s += fmaxf(kMargin - (P0 - N0), 0.0f);
        s += fmaxf(kMargin - (P0 - N1), 0.0f);
        s += fmaxf(kMargin - (P1 - N0), 0.0f);
        s += fmaxf(kMargin - (P1 - N1), 0.0f);
        return 0.25f * s;
    };

    const int ub = wid * kUsersPerWave;
    #define LDIDX(i) (((ub + (i) * 4) << 6) + (lane << 2))
    float4 ct = *reinterpret_cast<const float4*>(y_true + LDIDX(0));
    float4 cr = *reinterpret_cast<const float4*>(rnd    + LDIDX(0));
    float4 ch = *reinterpret_cast<const float4*>(y_hat  + LDIDX(0));

    float acc = 0.0f;
    #pragma unroll 1
    for (int it = 0; it < kIters; ++it) {
        const int nx = (it + 1 < kIters) ? it + 1 : it;
        // next-chunk loads: first USE is the scalar pin below (after
        // compute), so the scheduler issues them here and the vmcnt wait
        // lands post-compute.
        float4 nt = *reinterpret_cast<const float4*>(y_true + LDIDX(nx));
        float4 nr = *reinterpret_cast<const float4*>(rnd    + LDIDX(nx));
        float4 nh = *reinterpret_cast<const float4*>(y_hat  + LDIDX(nx));

        acc += process(ch, ct, cr);

        // keep-alive pin AFTER compute (scalar components: float4 "+v" is
        // unsupported on gfx950 -- R15 compile failure)
        asm volatile("" : "+v"(nt.x), "+v"(nt.y), "+v"(nt.z), "+v"(nt.w),
                          "+v"(nr.x), "+v"(nr.y), "+v"(nr.z), "+v"(nr.w),
                          "+v"(nh.x), "+v"(nh.y), "+v"(nh.z), "+v"(nh.w));
        ct = nt; cr = nr; ch = nh;
    }
    #undef LDIDX

    // acc uniform within each 16-lane group; sum the 4 group leaders
    float contrib = (t == 0) ? acc : 0.0f;
    contrib += __shfl_xor(contrib, 32);
    contrib += __shfl_xor(contrib, 16);

    if (lane == 0) wsum[wv] = contrib;
    __syncthreads();
    if (threadIdx.x == 0) {
        float tsum = 0.0f;
        #pragma unroll
        for (int i = 0; i < kWavesPerBlock; ++i) tsum += wsum[i];
        partials[blockIdx.x] = tsum;
    }
}

__global__ void prl_reduce_kernel(const float* __restrict__ partials,
                                  float* __restrict__ out)
{
    float tv = 0.0f;
    for (int i = threadIdx.x; i < kGrid; i += 256) tv += partials[i];
    #pragma unroll
    for (int s = 32; s > 0; s >>= 1) tv += __shfl_xor(tv, s);
    __shared__ float ws[4];
    if ((threadIdx.x & 63) == 0) ws[threadIdx.x >> 6] = tv;
    __syncthreads();
    if (threadIdx.x == 0) {
        out[0] = (ws[0] + ws[1] + ws[2] + ws[3]) * (1.0f / (float)kUsers);
    }
}

extern "C" void kernel_launch(void* const* d_in, const int* in_sizes, int n_in,
                              void* d_out, int out_size, void* d_ws, size_t ws_size,
                              hipStream_t stream) {
    const float* y_hat  = (const float*)d_in[0];
    const float* y_true = (const float*)d_in[1];
    const float* rnd    = (const float*)d_in[2];
    // d_in[3] = user_idx: contiguous equal-size segments -> never read
    float* partials = (float*)d_ws;          // kGrid floats = 8 KiB scratch
    float* out      = (float*)d_out;

    hipLaunchKernelGGL(prl_user_kernel, dim3(kGrid), dim3(kBlock), 0, stream,
                       y_hat, y_true, rnd, partials);
    hipLaunchKernelGGL(prl_reduce_kernel, dim3(1), dim3(256), 0, stream,
                       partials, out);
}

// Round 17
// 39.760 us; speedup vs baseline: 1.1742x; 1.1742x over previous
//
#include <hip/hip_runtime.h>

// PairwiseRankLoss: U=262144 users x G=64 items, K=2, MARGIN=0.3
// R17: 8 lanes/user x 8 items/lane (8 users/wave). Work-reduction round
// (the only lever that ever moved the bench: R5->R6). vs 16x4 layout:
//  - bitonic k=2,4 fully in-lane with COMPILE-TIME directions (zero masks)
//  - k=8 in-lane with direction in the sign (signed-space flips)
//  - only 4 cross-lane exchanges/body (k16:j8, k32:j16,j8, split), each a
//    single DPP via GF(2)^3 remap {1,2,4}->{1,2,7} inside 8-lane groups
//  - upper half descends automatically after k=32 (dir bit = l2) -> split
//    is mov_dpp(xor7)+fmin; sign state is 0 exactly at split time
//  - every instruction serves 8 users; issue-work/body (~800cyc) now
//    exceeds the critical path (~300cyc) -> wave fills its own bubbles
// Selection: index-embedded keys, in-lane top2-of-8 + 3 cross FOLD2;
// gather via per-user LDS y_hat row (uniform reads). Bit-exact semantics
// identical to the R9-R16 proven kernel. Two-stage deterministic reduce.

static constexpr int kUsers = 262144;
static constexpr int kBlock = 256;                  // 4 waves / block
static constexpr int kGrid  = 2048;
static constexpr int kWavesPerBlock = kBlock / 64;
static constexpr int kTotalWaves = kGrid * kWavesPerBlock;   // 8192
static constexpr int kUsersPerWave = kUsers / kTotalWaves;   // 32
static constexpr int kBodies = kUsersPerWave / 8;            // 4
static constexpr float kMargin = 0.3f;

template<int CTRL>
static __device__ __forceinline__ float movdppf(float x) {
    return __uint_as_float((unsigned)__builtin_amdgcn_mov_dpp(
        (int)__float_as_uint(x), CTRL, 0xF, 0xF, false));
}
template<int CTRL>
static __device__ __forceinline__ unsigned movdppu(unsigned x) {
    return (unsigned)__builtin_amdgcn_mov_dpp((int)x, CTRL, 0xF, 0xF, false);
}
static __device__ __forceinline__ float xorf(float x, unsigned m) {
    return __uint_as_float(__float_as_uint(x) ^ m);
}
static __device__ __forceinline__ float cnd(float mx, float mn,
                                            unsigned long long keep) {
    float d;
    asm("v_cndmask_b32 %0, %1, %2, %3" : "=v"(d) : "v"(mx), "v"(mn), "s"(keep));
    return d;
}
template<int CTRL>
static __device__ __forceinline__ float cexd(float w, unsigned long long keep) {
    const float p = movdppf<CTRL>(w);
    return cnd(fmaxf(w, p), fminf(w, p), keep);
}
static __device__ __forceinline__ unsigned umax_(unsigned a, unsigned b){ return a>b?a:b; }
static __device__ __forceinline__ unsigned umin_(unsigned a, unsigned b){ return a<b?a:b; }

#define CE2A(a, b) { float mn_=fminf(a,b), mx_=fmaxf(a,b); (a)=mn_; (b)=mx_; }
#define CE2D(a, b) { float mn_=fminf(a,b), mx_=fmaxf(a,b); (a)=mx_; (b)=mn_; }
#define FLIPALL(m) { w0=xorf(w0,m); w1=xorf(w1,m); w2=xorf(w2,m); w3=xorf(w3,m); \
                     w4=xorf(w4,m); w5=xorf(w5,m); w6=xorf(w6,m); w7=xorf(w7,m); }
#define CEXALL(CTRL, keep) { w0=cexd<CTRL>(w0,keep); w1=cexd<CTRL>(w1,keep); \
                             w2=cexd<CTRL>(w2,keep); w3=cexd<CTRL>(w3,keep); \
                             w4=cexd<CTRL>(w4,keep); w5=cexd<CTRL>(w5,keep); \
                             w6=cexd<CTRL>(w6,keep); w7=cexd<CTRL>(w7,keep); }
#define INL_J4A    { CE2A(w0,w4); CE2A(w1,w5); CE2A(w2,w6); CE2A(w3,w7); }
#define INL_J2A    { CE2A(w0,w2); CE2A(w1,w3); CE2A(w4,w6); CE2A(w5,w7); }
#define INL_J1A    { CE2A(w0,w1); CE2A(w2,w3); CE2A(w4,w5); CE2A(w6,w7); }
#define FOLD2(m1, m2, CTRL) { \
    unsigned q1_ = movdppu<CTRL>(m1), q2_ = movdppu<CTRL>(m2); \
    unsigned lo_ = umin_(m1, q1_); \
    m1 = umax_(m1, q1_); \
    m2 = umax_(lo_, umax_(m2, q2_)); }

__global__ __launch_bounds__(kBlock, 8)
void prl_user_kernel(const float* __restrict__ y_hat,
                     const float* __restrict__ y_true,
                     const float* __restrict__ rnd,
                     float* __restrict__ partials)
{
    const int lane = threadIdx.x & 63;
    const int wv   = threadIdx.x >> 6;
    const int wid  = (blockIdx.x * kBlock + threadIdx.x) >> 6;
    const int p    = lane & 7;           // physical lane within user
    const int g3   = lane >> 3;          // user group (0..7) within wave

    // logical lane bits for map {1,2,4}->{1,2,7}: l = M^-1(p)
    const int l2 = (p >> 2) & 1;
    const int l0 = (p & 1) ^ l2;
    const int l1 = ((p >> 1) & 1) ^ l2;

    const unsigned SGN = 0x80000000u;
    const unsigned flip8  = l0 ? SGN : 0u;          // enter k=8 (dir l0)
    const unsigned flip16 = (l0 ^ l1) ? SGN : 0u;   // enter k=16 (dir l1)
    const unsigned flip32 = (l1 ^ l2) ? SGN : 0u;   // enter k=32 (dir l2)
    const unsigned unfl   = l2 ? SGN : 0u;          // back to true space
    const unsigned long long keep1 = __ballot(l0 == 0);  // logical j=8
    const unsigned long long keep2 = __ballot(l1 == 0);  // logical j=16

    const unsigned cb = 63u - ((unsigned)p << 3);   // 63 - item_idx base

    // y_hat gather table: [wave][user][68 (pad)] = 8.5 KB/block
    __shared__ __align__(16) float yh_tab[kWavesPerBlock][8][68];
    __shared__ float wsum[kWavesPerBlock];
    float* tg = &yh_tab[wv][g3][0];

    const int ub = wid * kUsersPerWave;

    float acc = 0.0f;
    #pragma unroll 1
    for (int b = 0; b < kBodies; ++b) {
        const int base = ((ub + b * 8) << 6) + (lane << 3);
        const float4 vha = *reinterpret_cast<const float4*>(y_hat + base);
        const float4 vhb = *reinterpret_cast<const float4*>(y_hat + base + 4);
        const float4 vta = *reinterpret_cast<const float4*>(y_true + base);
        const float4 vtb = *reinterpret_cast<const float4*>(y_true + base + 4);
        const float4 vra = *reinterpret_cast<const float4*>(rnd + base);
        const float4 vrb = *reinterpret_cast<const float4*>(rnd + base + 4);

        // stage y_hat row for winner gather
        *reinterpret_cast<float4*>(tg + (p << 3))     = vha;
        *reinterpret_cast<float4*>(tg + (p << 3) + 4) = vhb;

        // selection keys early (releases vr regs): (r&~63)|(63 - (8p+s))
        const unsigned kk0 = (__float_as_uint(vra.x) & ~63u) | cb;
        const unsigned kk1 = (__float_as_uint(vra.y) & ~63u) | (cb - 1u);
        const unsigned kk2 = (__float_as_uint(vra.z) & ~63u) | (cb - 2u);
        const unsigned kk3 = (__float_as_uint(vra.w) & ~63u) | (cb - 3u);
        const unsigned kk4 = (__float_as_uint(vrb.x) & ~63u) | (cb - 4u);
        const unsigned kk5 = (__float_as_uint(vrb.y) & ~63u) | (cb - 5u);
        const unsigned kk6 = (__float_as_uint(vrb.z) & ~63u) | (cb - 6u);
        const unsigned kk7 = (__float_as_uint(vrb.w) & ~63u) | (cb - 7u);

        // ---- bitonic sort of 64 items; q = 8*L + s ----
        float w0 = vta.x, w1 = vta.y, w2 = vta.z, w3 = vta.w;
        float w4 = vtb.x, w5 = vtb.y, w6 = vtb.z, w7 = vtb.w;
        // k=2 (dir bit1(s), compile-time)
        CE2A(w0,w1); CE2D(w2,w3); CE2A(w4,w5); CE2D(w6,w7);
        // k=4 (dir bit2(s), compile-time)
        CE2A(w0,w2); CE2A(w1,w3); CE2D(w4,w6); CE2D(w5,w7);   // j=2
        CE2A(w0,w1); CE2A(w2,w3); CE2D(w4,w5); CE2D(w6,w7);   // j=1
        // k=8 (dir l0, in sign)
        FLIPALL(flip8);
        INL_J4A; INL_J2A; INL_J1A;
        // k=16 (dir l1)
        FLIPALL(flip16);
        CEXALL(0xB1, keep1);                                  // j=8 (xor1)
        INL_J4A; INL_J2A; INL_J1A;
        // k=32 (dir l2)
        FLIPALL(flip32);
        CEXALL(0x4E, keep2);                                  // j=16 (xor2)
        CEXALL(0xB1, keep1);                                  // j=8
        INL_J4A; INL_J2A; INL_J1A;
        // true space: lower half asc, upper half desc (dir bit = l2)
        FLIPALL(unfl);
        // split: partner q^32 = logical lane^4 = physical xor7; min only
        const float s0 = fminf(w0, movdppf<0x141>(w0));
        const float s1 = fminf(w1, movdppf<0x141>(w1));
        const float s2 = fminf(w2, movdppf<0x141>(w2));
        const float s3 = fminf(w3, movdppf<0x141>(w3));
        const float s4 = fminf(w4, movdppf<0x141>(w4));
        const float s5 = fminf(w5, movdppf<0x141>(w5));
        const float s6 = fminf(w6, movdppf<0x141>(w6));
        const float s7 = fminf(w7, movdppf<0x141>(w7));
        // a31 = max of lower-32 multiset (dup'd across halves)
        float m = fmaxf(fmaxf(fmaxf(s0, s1), fmaxf(s2, s3)),
                        fmaxf(fmaxf(s4, s5), fmaxf(s6, s7)));
        m = fmaxf(m, movdppf<0xB1>(m));
        m = fmaxf(m, movdppf<0x4E>(m));
        m = fmaxf(m, movdppf<0x141>(m));
        const float a31 = m;                    // uniform within 8-lane user

        // ---- pos mask + per-side keys ----
        const bool p0m = vta.x > a31, p1m = vta.y > a31,
                   p2m = vta.z > a31, p3m = vta.w > a31,
                   p4m = vtb.x > a31, p5m = vtb.y > a31,
                   p6m = vtb.z > a31, p7m = vtb.w > a31;

        auto top2 = [&](unsigned k0, unsigned k1, unsigned k2, unsigned k3,
                        unsigned k4, unsigned k5, unsigned k6, unsigned k7,
                        unsigned& m1, unsigned& m2) {
            const unsigned h1 = umax_(k0,k1), q1 = umin_(k0,k1);
            const unsigned h2 = umax_(k2,k3), q2 = umin_(k2,k3);
            const unsigned h3 = umax_(k4,k5), q3 = umin_(k4,k5);
            const unsigned h4 = umax_(k6,k7), q4 = umin_(k6,k7);
            const unsigned ma = umax_(h1,h2);
            const unsigned sa = umax_(umin_(h1,h2), umax_(q1,q2));
            const unsigned mb = umax_(h3,h4);
            const unsigned sb = umax_(umin_(h3,h4), umax_(q3,q4));
            m1 = umax_(ma,mb);
            m2 = umax_(umin_(ma,mb), umax_(sa,sb));
            FOLD2(m1, m2, 0xB1);    // xor1
            FOLD2(m1, m2, 0x4E);    // xor2
            FOLD2(m1, m2, 0x141);   // xor7 -> uniform over 8-lane user
        };
        unsigned pm1, pm2, nm1, nm2;
        top2(p0m ? kk0 : 0u, p1m ? kk1 : 0u, p2m ? kk2 : 0u, p3m ? kk3 : 0u,
             p4m ? kk4 : 0u, p5m ? kk5 : 0u, p6m ? kk6 : 0u, p7m ? kk7 : 0u,
             pm1, pm2);
        top2(p0m ? 0u : kk0, p1m ? 0u : kk1, p2m ? 0u : kk2, p3m ? 0u : kk3,
             p4m ? 0u : kk4, p5m ? 0u : kk5, p6m ? 0u : kk6, p7m ? 0u : kk7,
             nm1, nm2);

        // winner gather: idx = (key&63)^63; uniform LDS reads per user
        const float P0 = tg[(pm1 & 63u) ^ 63u];
        const float P1 = tg[(pm2 & 63u) ^ 63u];
        const float N0 = tg[(nm1 & 63u) ^ 63u];
        const float N1 = tg[(nm2 & 63u) ^ 63u];

        float s = 0.0f;
        s += fmaxf(kMargin - (P0 - N0), 0.0f);
        s += fmaxf(kMargin - (P0 - N1), 0.0f);
        s += fmaxf(kMargin - (P1 - N0), 0.0f);
        s += fmaxf(kMargin - (P1 - N1), 0.0f);
        acc = fmaf(0.25f, s, acc);
    }

    // acc uniform within each 8-lane user; sum the 8 group leaders
    float contrib = (p == 0) ? acc : 0.0f;
    contrib += __shfl_xor(contrib, 8);
    contrib += __shfl_xor(contrib, 16);
    contrib += __shfl_xor(contrib, 32);

    if (lane == 0) wsum[wv] = contrib;
    __syncthreads();
    if (threadIdx.x == 0) {
        float tsum = 0.0f;
        #pragma unroll
        for (int i = 0; i < kWavesPerBlock; ++i) tsum += wsum[i];
        partials[blockIdx.x] = tsum;
    }
}

__global__ void prl_reduce_kernel(const float* __restrict__ partials,
                                  float* __restrict__ out)
{
    float tv = 0.0f;
    for (int i = threadIdx.x; i < kGrid; i += 256) tv += partials[i];
    #pragma unroll
    for (int s = 32; s > 0; s >>= 1) tv += __shfl_xor(tv, s);
    __shared__ float ws[4];
    if ((threadIdx.x & 63) == 0) ws[threadIdx.x >> 6] = tv;
    __syncthreads();
    if (threadIdx.x == 0) {
        out[0] = (ws[0] + ws[1] + ws[2] + ws[3]) * (1.0f / (float)kUsers);
    }
}

extern "C" void kernel_launch(void* const* d_in, const int* in_sizes, int n_in,
                              void* d_out, int out_size, void* d_ws, size_t ws_size,
                              hipStream_t stream) {
    const float* y_hat  = (const float*)d_in[0];
    const float* y_true = (const float*)d_in[1];
    const float* rnd    = (const float*)d_in[2];
    // d_in[3] = user_idx: contiguous equal-size segments -> never read
    float* partials = (float*)d_ws;          // kGrid floats = 8 KiB scratch
    float* out      = (float*)d_out;

    hipLaunchKernelGGL(prl_user_kernel, dim3(kGrid), dim3(kBlock), 0, stream,
                       y_hat, y_true, rnd, partials);
    hipLaunchKernelGGL(prl_reduce_kernel, dim3(1), dim3(256), 0, stream,
                       partials, out);
}